// Round 6
// baseline (374.238 us; speedup 1.0000x reference)
//
#include <hip/hip_runtime.h>
#include <math.h>

// dims
#define BS 16
#define C_ 684
#define Hh 32
#define Ww 128
#define HW 4096
#define Qc 256
#define NP 512
#define Nn 256
#define NKT 26            // K-tiles of 32 (832 total: 684 x-ch + 121 taps + pad)
#define NB 64             // pixels per gemm block

// workspace layout (float offsets)
#define WS_BETA 0            // 16*4096 = 65536
#define WS_BIAS 65536        // 16*512  = 8192
#define WS_EEXP 73728        // 16*4096 = 65536
#define WS_E    139264       // 16*4096 = 65536
#define WS_INV  204800       // 16
#define WS_ASW  204816       // 26*4*512*8 shorts = 425984 shorts = 212992 floats

typedef __attribute__((ext_vector_type(8))) short bf16x8;
typedef __attribute__((ext_vector_type(4))) float f32x4;

static __device__ __forceinline__ short f2bf(float f) {
    unsigned u = __builtin_bit_cast(unsigned, f);
    u += 0x7fff + ((u >> 16) & 1);          // RNE
    return (short)(u >> 16);
}

static __device__ __forceinline__ float fast_tanh(float v) {
    float ax = fabsf(v);
    float t = __expf(-2.f * ax);            // in (0,1], no overflow
    float th = (1.f - t) * __builtin_amdgcn_rcpf(1.f + t);
    return copysignf(th, v);
}

// ---- fused prep: beta, A-swizzle, bias, e-zero -------------------------
// grid = 256 + 1664 + 32 + 256 = 2208 blocks
__global__ void k_prep(const float* __restrict__ alpha, const float* __restrict__ ua,
                       const float* __restrict__ ufw, const float* __restrict__ qw,
                       const float* __restrict__ st, const float* __restrict__ waw,
                       const float* __restrict__ wab, const float* __restrict__ ufb,
                       const float* __restrict__ qb, const float* __restrict__ uab,
                       float* __restrict__ beta, short* __restrict__ a_sw,
                       float* __restrict__ bias, float* __restrict__ e) {
    int part = blockIdx.x, tid = threadIdx.x;
    if (part < 256) {
        // beta = sum_t alpha
        int idx = part * 256 + tid;
        int b = idx >> 12, n = idx & 4095;
        const float* a = alpha + (size_t)b * 4 * HW + n;
        beta[idx] = a[0] + a[HW] + a[2 * HW] + a[3 * HW];
    } else if (part < 1920) {
        // a_sw[kt][g][m][j] = A[k][m] bf16, k = kt*32+g*8+j
        int idx = (part - 256) * 256 + tid;          // < 425984
        int j = idx & 7, m = (idx >> 3) & 511, g = (idx >> 12) & 3, kt = idx >> 14;
        int k = kt * 32 + g * 8 + j;
        float v = 0.f;
        if (k < C_) {
            v = ua[m * C_ + k];
        } else if (k < C_ + 121) {
            int tap = k - C_;
            const float* ur = ufw + m * Qc;
            float s = 0.f;
            for (int q = 0; q < Qc; ++q) s += ur[q] * qw[q * 121 + tap];
            v = s;
        }
        a_sw[idx] = f2bf(v);
    } else if (part < 1952) {
        // bias[b][p]
        int idx = (part - 1920) * 256 + tid;         // < 8192
        int b = idx >> 9, p = idx & 511;
        float s = wab[p] + ufb[p] + uab[p];
        const float* sv = st + b * Nn;
        const float* wr = waw + p * Nn;
        for (int n = 0; n < Nn; ++n) s += sv[n] * wr[n];
        const float* ur = ufw + p * Qc;
        for (int q = 0; q < Qc; ++q) s += ur[q] * qb[q];
        bias[idx] = s;
    } else {
        // e = 0 (atomicAdd target)
        e[(part - 1952) * 256 + tid] = 0.f;
    }
}

// ---- fused MFMA GEMM + tanh/Va partial epilogue -> atomicAdd e ---------
// block: M=256 (half of p) x N=64, K=832. grid (n-tile, m-half, batch).
// Wave tile 64x64 -> acc = 64 AGPRs (vs 128) => 3 waves/SIMD occupancy.
__launch_bounds__(256, 3)
__global__ void k_gemm(const short* __restrict__ a_sw, const float* __restrict__ x,
                       const float* __restrict__ beta, const float* __restrict__ bias,
                       const float* __restrict__ vaw, const float* __restrict__ vab,
                       float* __restrict__ e) {
    __shared__ short Bs[2][4 * NB * 8];  // 2 x 4 KB : [g][n][j]
    __shared__ float ered[4][NB];

    const int tid = threadIdx.x;
    const int lane = tid & 63, wid = tid >> 6;
    const int b = blockIdx.z, my = blockIdx.y, n0 = blockIdx.x * NB;
    const int q = lane >> 4, r = lane & 15;
    const int m0 = my * 256;                 // row base for this block

    // staging role: pixel sn, k-group sg (wave-uniform), 8 j's
    const int sn = tid & 63;
    const int sg = tid >> 6;
    const int n_glob = n0 + sn;
    const int pr = n_glob >> 7, pc = n_glob & 127;
    const float* xb = x + (size_t)b * C_ * HW + n_glob;
    const float* betab = beta + b * HW;

    f32x4 acc[4][4] = {};
    float fv[2][8];

    #define LDSTAGE(KT, DST)                                                  \
    {                                                                         \
        int kbase = (KT) * 32 + sg * 8;                                       \
        _Pragma("unroll")                                                     \
        for (int j = 0; j < 8; ++j) {                                         \
            int k = kbase + j;                                                \
            float f = 0.f;                                                    \
            if (k < C_) {                                                     \
                f = xb[(size_t)k * HW];                                       \
            } else if (k < C_ + 121) {                                        \
                int tap = k - C_;                                             \
                int di = tap / 11, dj = tap - di * 11;                        \
                int rr = pr + di - 5, cc = pc + dj - 5;                       \
                if (rr >= 0 && rr < Hh && cc >= 0 && cc < Ww)                 \
                    f = betab[rr * 128 + cc];                                 \
            }                                                                 \
            (DST)[j] = f;                                                     \
        }                                                                     \
    }

    LDSTAGE(0, fv[0]);
    LDSTAGE(1, fv[1]);

    // wave's A base: rows m0 + wid*64 + ms*16 + r, k-group q
    const short* ap = a_sw + (size_t)(q * NP + m0 + wid * 64 + r) * 8;

    #pragma unroll 2
    for (int kt = 0; kt < NKT; ++kt) {
        // A fragments first: L2 latency covered by pack+barrier+ds_read
        bf16x8 af[4];
        const short* ak = ap + (size_t)kt * 4 * NP * 8;
        #pragma unroll
        for (int ms = 0; ms < 4; ++ms)
            af[ms] = *(const bf16x8*)(ak + ms * 16 * 8);

        // pack B values (prefetched 2 iters ago) and store to LDS
        {
            const float* f = fv[kt & 1];
            unsigned pk[4];
            #pragma unroll
            for (int h = 0; h < 4; ++h)
                pk[h] = (unsigned)(unsigned short)f2bf(f[2 * h]) |
                        ((unsigned)(unsigned short)f2bf(f[2 * h + 1]) << 16);
            *(uint4*)&Bs[kt & 1][(sg * NB + sn) * 8] = make_uint4(pk[0], pk[1], pk[2], pk[3]);
        }
        __syncthreads();   // single barrier per kt (dbuf makes WAR safe)

        bf16x8 bf[4];
        #pragma unroll
        for (int ns = 0; ns < 4; ++ns)
            bf[ns] = *(const bf16x8*)&Bs[kt & 1][(q * NB + ns * 16 + r) * 8];

        // prefetch staging values for kt+2 (overlaps with MFMA below)
        if (kt < NKT - 2) LDSTAGE(kt + 2, fv[kt & 1]);

        #pragma unroll
        for (int ms = 0; ms < 4; ++ms)
            #pragma unroll
            for (int ns = 0; ns < 4; ++ns)
                acc[ms][ns] = __builtin_amdgcn_mfma_f32_16x16x32_bf16(af[ms], bf[ns], acc[ms][ns], 0, 0, 0);
    }
    #undef LDSTAGE

    // ---- epilogue: partial e = sum_{rows of this half} Va*tanh(acc+bias) ----
    // C/D layout: col = lane&15, row = (lane>>4)*4 + reg
    float es[4] = {0.f, 0.f, 0.f, 0.f};
    #pragma unroll
    for (int ms = 0; ms < 4; ++ms) {
        #pragma unroll
        for (int reg = 0; reg < 4; ++reg) {
            int row = m0 + wid * 64 + ms * 16 + q * 4 + reg;
            float bv = bias[b * NP + row];
            float vv = vaw[row];
            #pragma unroll
            for (int ns = 0; ns < 4; ++ns)
                es[ns] += vv * fast_tanh(acc[ms][ns][reg] + bv);
        }
    }
    #pragma unroll
    for (int ns = 0; ns < 4; ++ns) {
        es[ns] += __shfl_xor(es[ns], 16, 64);
        es[ns] += __shfl_xor(es[ns], 32, 64);
    }
    if (lane < 16) {
        #pragma unroll
        for (int ns = 0; ns < 4; ++ns) ered[wid][ns * 16 + r] = es[ns];
    }
    __syncthreads();
    if (tid < NB) {          // exactly wave 0
        float s = ered[0][tid] + ered[1][tid] + ered[2][tid] + ered[3][tid];
        if (my == 0) s += vab[0];
        atomicAdd(&e[b * HW + n0 + tid], s);
    }
}

// ---- mid: eexp = exp(e), inv[b] = 1/(sum + 1e-8) -----------------------
__global__ void k_mid(const float* __restrict__ e, float* __restrict__ eexp,
                      float* __restrict__ inv) {
    __shared__ float sred[256];
    int b = blockIdx.x, tid = threadIdx.x;
    float vloc[16];
    float ps = 0.f;
#pragma unroll
    for (int k = 0; k < 16; ++k) {
        vloc[k] = expf(e[b * HW + tid + k * 256]);
        ps += vloc[k];
    }
#pragma unroll
    for (int k = 0; k < 16; ++k) eexp[b * HW + tid + k * 256] = vloc[k];
    sred[tid] = ps;
    __syncthreads();
    for (int s = 128; s > 0; s >>= 1) {
        if (tid < s) sred[tid] += sred[tid + s];
        __syncthreads();
    }
    if (tid == 0) inv[b] = 1.f / (sred[0] + 1e-8f);
}

// ---- finish: context rows (wave-per-row) + alpha writeback -------------
__global__ void k_finish(const float* __restrict__ x, const float* __restrict__ eexp,
                         const float* __restrict__ inv, float* __restrict__ ctx,
                         float* __restrict__ aout) {
    int part = blockIdx.x, b = blockIdx.y, tid = threadIdx.x;
    float iv = inv[b];
    if (part == 171) {
        for (int k = tid; k < HW; k += 256) aout[b * HW + k] = eexp[b * HW + k] * iv;
        return;
    }
    int wid = tid >> 6, lane = tid & 63;
    int c = part * 4 + wid;                          // < 684
    const float4* xr = (const float4*)(x + ((size_t)b * C_ + c) * HW);
    const float4* er = (const float4*)(eexp + b * HW);
    float acc = 0.f;
    #pragma unroll 8
    for (int k = lane; k < 1024; k += 64) {
        float4 xv = xr[k], ev = er[k];
        acc += xv.x * ev.x + xv.y * ev.y + xv.z * ev.z + xv.w * ev.w;
    }
    #pragma unroll
    for (int off = 32; off > 0; off >>= 1) acc += __shfl_xor(acc, off, 64);
    if (lane == 0) ctx[b * C_ + c] = acc * iv;
}

extern "C" void kernel_launch(void* const* d_in, const int* in_sizes, int n_in,
                              void* d_out, int out_size, void* d_ws, size_t ws_size,
                              hipStream_t stream) {
    const float* x      = (const float*)d_in[0];
    const float* st     = (const float*)d_in[1];
    const float* alpha  = (const float*)d_in[2];
    const float* convQw = (const float*)d_in[3];
    const float* convQb = (const float*)d_in[4];
    const float* Waw    = (const float*)d_in[5];
    const float* Wab    = (const float*)d_in[6];
    const float* Uaw    = (const float*)d_in[7];
    const float* Uab    = (const float*)d_in[8];
    const float* Ufw    = (const float*)d_in[9];
    const float* Ufb    = (const float*)d_in[10];
    const float* Vaw    = (const float*)d_in[11];
    const float* Vab    = (const float*)d_in[12];

    float* ws   = (float*)d_ws;
    float* beta = ws + WS_BETA;
    float* bias = ws + WS_BIAS;
    float* eexp = ws + WS_EEXP;
    float* e    = ws + WS_E;
    float* inv  = ws + WS_INV;
    short* a_sw = (short*)(ws + WS_ASW);

    float* ctx  = (float*)d_out;             // [16, 684]
    float* aout = (float*)d_out + BS * C_;   // [16, 4096]

    k_prep<<<2208, 256, 0, stream>>>(alpha, Uaw, Ufw, convQw, st, Waw, Wab, Ufb,
                                     convQb, Uab, beta, a_sw, bias, e);
    k_gemm<<<dim3(HW / NB, 2, BS), 256, 0, stream>>>(a_sw, x, beta, bias, Vaw, Vab, e);
    k_mid<<<BS, 256, 0, stream>>>(e, eexp, inv);
    k_finish<<<dim3(172, BS), 256, 0, stream>>>(x, eexp, inv, ctx, aout);
}